// Round 9
// baseline (167.016 us; speedup 1.0000x reference)
//
#include <hip/hip_runtime.h>
#include <hip/hip_bf16.h>

// RadarSecondStageGenerator — MFMA fp16, round 9: LDS bank-conflict fix
// (position stride 32 -> 34 halfs; 68 B = 17 words, coprime with 32 banks),
// LDS aliasing for s_x/s_hc (27.2 KB total -> up to 6 blocks/CU).
//
// h0 == 0 ⇒ flow/warp/w_ret branch dead; network = conv3x3(24->8) ->
// conv3x3(8->24) -> GRU gates (h2h == b_ret) -> conv1x1(8->12).
//
// conv_in im2col: M = 324 x-halo px (21 tiles), N = 8, K = 9 taps x 32 ch
//   (ch 0..11 radar, 12..23 pred, 24 = ones channel carrying b_in at the
//   center tap, 25..31 zero pad) -> 9 MFMA (16x16x32) per M-tile.
// i2h: M = 256 px (16 tiles), N = 24 (2 N-tiles), K = 12 taps x 8 ch (3 steps).
// Fragment layouts (HW-verified): A[m=lane&15][k=quad*8+j], C[row=quad*4+reg][col=lane&15].

typedef __fp16   h2f __attribute__((ext_vector_type(2)));   // cvt_pkrtz return type
typedef _Float16 v8h __attribute__((ext_vector_type(8)));
typedef float    v4f __attribute__((ext_vector_type(4)));

#define HW 128
#define SPITCH 34        // halfs per staged position: 68 B, coprime bank spread

#define WB_HOFF 4608     // half-index of i2h B-frags in ws
#define FLT_OFF 16384    // byte offset of float params in ws
#define N_PREP  7820     // 4608 + 3072 halfs, then 140 floats

__global__ __launch_bounds__(256)
void prep(const float* __restrict__ w_in,  const float* __restrict__ b_in,
          const float* __restrict__ w_i2h, const float* __restrict__ b_i2h,
          const float* __restrict__ b_ret, const float* __restrict__ w_out,
          const float* __restrict__ b_out, void* __restrict__ ws)
{
    int idx = blockIdx.x * 256 + threadIdx.x;
    _Float16* wh = (_Float16*)ws;
    float* fw = (float*)((char*)ws + FLT_OFF);
    if (idx < 4608) {                       // conv_in B-frags [s9][lane64][j8]
        int j = idx & 7, r = idx >> 3;
        int lane = r & 63, s = r >> 6;      // s = tap 0..8
        int quad = lane >> 4, n = lane & 15;
        int ch = quad * 8 + j;              // k within step = channel 0..31
        float v = 0.f;
        if (n < 8) {
            if (ch < 24)                 v = w_in[n*216 + ch*9 + s];
            else if (ch == 24 && s == 4) v = b_in[n];   // ones-channel bias
        }
        wh[idx] = (_Float16)v;
    } else if (idx < 7680) {                // i2h B-frags [s3][nt2][lane64][j8]
        int i2 = idx - 4608;
        int j = i2 & 7, r = i2 >> 3;
        int lane = r & 63; r >>= 6;
        int nt = r & 1, s = r >> 1;
        int quad = lane >> 4, n = lane & 15;
        int kk = s * 32 + quad * 8 + j;     // K: tap-major, 8 ch per tap
        int t = kk >> 3, m = kk & 7;        // tap 0..11 (9..11 pad)
        int o = nt * 16 + n;
        float v = (t < 9 && o < 24) ? w_i2h[o*72 + m*9 + t] : 0.f;
        wh[WB_HOFF + i2] = (_Float16)v;
    } else if (idx < N_PREP) {
        int j = idx - 7680;
        float v;
        if (j < 32) {                       // combined gate biases
            int c = j & 7, sel = j >> 3;
            v = (sel==0) ? b_i2h[c]    + b_ret[c]
              : (sel==1) ? b_i2h[8+c]  + b_ret[8+c]
              : (sel==2) ? b_i2h[16+c] : b_ret[16+c];
        } else if (j < 128) v = w_out[j-32];
        else                v = b_out[j-128];
        fw[j] = v;
    }
}

__device__ __forceinline__ void pack_store(_Float16* dst, const float* v, bool ones)
{
    union { h2f h2[16]; v8h h8[4]; } u;
#pragma unroll
    for (int k = 0; k < 12; ++k)
        u.h2[k] = __builtin_amdgcn_cvt_pkrtz(v[2 * k], v[2 * k + 1]);
    u.h2[12] = __builtin_amdgcn_cvt_pkrtz(ones ? 1.f : 0.f, 0.f);
#pragma unroll
    for (int k = 13; k < 16; ++k) u.h2[k] = (h2f)0.f;
#pragma unroll
    for (int k = 0; k < 4; ++k) *(v8h*)&dst[8 * k] = u.h8[k];
}

__global__ __launch_bounds__(256, 6)
void radar2_mfma(const float* __restrict__ radar,  // (32,12,128,128)
                 const float* __restrict__ pred,   // (32,12,128,128)
                 const void*  __restrict__ ws,
                 float* __restrict__ out)          // (32,12,128,128)
{
    // Pool: s_in [400][SPITCH] f16 = 27200 B.
    // s_x  [336][8] f16 (5376 B)  aliases pool head  (s_in rows 0..78, dead
    //   after the post-conv_in barrier).
    // s_hc [256][9] f32 (9216 B)  at pool+5376 (disjoint from s_x, also dead
    //   s_in territory).
    __shared__ __align__(16) char pool[400 * SPITCH * 2];
    _Float16* s_in = (_Float16*)pool;
    _Float16* s_x  = (_Float16*)pool;
    float*    s_hc = (float*)(pool + 5376);

    const _Float16* wh = (const _Float16*)ws;
    const float* fw = (const float*)((const char*)ws + FLT_OFF);

    const int tid  = threadIdx.x;
    const int lane = tid & 63;
    const int wave = tid >> 6;
    const int quad = lane >> 4;
    const int col  = lane & 15;

    // XCD-locality swizzle: id&7 = XCD (round-robin dispatch); each XCD's
    // 256-block stripe covers 4 whole batches -> halo reuse stays in one L2.
    const int id   = blockIdx.x;
    const int b    = (id & 7) * 4 + ((id >> 3) >> 6);
    const int tile = (id >> 3) & 63;
    const int ty0  = (tile >> 3) << 4;
    const int tx0  = (tile & 7) << 4;

    // ---- stage halo-2 patch, 25 live channels, channel-last; two slots with
    // all global loads issued before converts (max memory-level parallelism) ----
    const float* rb = radar + (((size_t)b * 12) << 14);
    const float* pb = pred  + (((size_t)b * 12) << 14);

    const int r0 = tid, r1 = tid + 256;
    const int ly0 = r0 / 20, lx0 = r0 - 20 * ly0;
    const int gy0 = ty0 + ly0 - 2, gx0 = tx0 + lx0 - 2;
    const bool in0 = ((unsigned)gy0 < HW) & ((unsigned)gx0 < HW);
    const int off0 = (gy0 << 7) + gx0;
    const bool has1 = (r1 < 400);
    const int ly1 = r1 / 20, lx1 = r1 - 20 * ly1;
    const int gy1 = ty0 + ly1 - 2, gx1 = tx0 + lx1 - 2;
    const bool in1 = has1 & ((unsigned)gy1 < HW) & ((unsigned)gx1 < HW);
    const int off1 = (gy1 << 7) + gx1;

    float va[24], vb24[24];
#pragma unroll
    for (int c = 0; c < 12; ++c) {
        va[c]      = in0 ? rb[((size_t)c << 14) + off0] : 0.f;
        va[12 + c] = in0 ? pb[((size_t)c << 14) + off0] : 0.f;
    }
#pragma unroll
    for (int c = 0; c < 12; ++c) {
        vb24[c]      = in1 ? rb[((size_t)c << 14) + off1] : 0.f;
        vb24[12 + c] = in1 ? pb[((size_t)c << 14) + off1] : 0.f;
    }
    pack_store(&s_in[r0 * SPITCH], va, in0);
    if (has1) pack_store(&s_in[r1 * SPITCH], vb24, in1);

    // conv_in B-frags — issued after staging stores; latency hides in barrier
    v8h bfA[9];
#pragma unroll
    for (int s = 0; s < 9; ++s) bfA[s] = *(const v8h*)&wh[(s * 64 + lane) * 8];
    __syncthreads();

    // ---- conv_in: 21 M-tiles over 4 waves, 9 MFMA each ----
    int pbase[6];
#pragma unroll
    for (int t = 0; t < 6; ++t) {
        int p = (wave + 4 * t) * 16 + col; if (p > 323) p = 323;
        pbase[t] = ((p / 18) * 20 + (p % 18)) * SPITCH + quad * 8;
    }
    v4f accA[6];
#pragma unroll
    for (int t = 0; t < 6; ++t) accA[t] = (v4f){0.f, 0.f, 0.f, 0.f};
#pragma unroll
    for (int t = 0; t < 6; ++t) {
        if (wave + 4 * t < 21) {
#pragma unroll
            for (int s = 0; s < 9; ++s) {
                v8h a = *(const v8h*)&s_in[pbase[t] + ((s / 3) * 20 + (s % 3)) * SPITCH];
                accA[t] = __builtin_amdgcn_mfma_f32_16x16x32_f16(a, bfA[s], accA[t], 0, 0, 0);
            }
        }
    }
    __syncthreads();   // all s_in reads complete before s_x overwrites pool head

    // ---- write s_x (x zero-padded outside the image) ----
    if (col < 8) {
#pragma unroll
        for (int t = 0; t < 6; ++t) {
            int mt = wave + 4 * t;
            if (mt < 21) {
#pragma unroll
                for (int r = 0; r < 4; ++r) {
                    int pa = mt * 16 + quad * 4 + r;
                    int py = pa / 18, px = pa - 18 * py;
                    bool ok = (pa < 324) &&
                              ((unsigned)(ty0 + py - 1) < HW) &&
                              ((unsigned)(tx0 + px - 1) < HW);
                    s_x[pa * 8 + col] = (_Float16)(ok ? accA[t][r] : 0.f);
                }
            }
        }
    }
    __syncthreads();

    // ---- i2h: 16 M-tiles, 3 K-steps, 2 N-tiles ----
    int toff2[3];
#pragma unroll
    for (int s = 0; s < 3; ++s) {
        int t = s * 4 + quad;
        toff2[s] = (t < 9) ? ((t / 3) * 18 + (t % 3)) * 8 : 0;
    }
    v8h bfB[3][2];
#pragma unroll
    for (int s = 0; s < 3; ++s)
#pragma unroll
        for (int nt = 0; nt < 2; ++nt)
            bfB[s][nt] = *(const v8h*)&wh[WB_HOFF + ((s * 2 + nt) * 64 + lane) * 8];

    v4f acc0[4], acc1[4];
#pragma unroll
    for (int t = 0; t < 4; ++t) {
        acc0[t] = (v4f){0.f, 0.f, 0.f, 0.f};
        acc1[t] = (v4f){0.f, 0.f, 0.f, 0.f};
    }
#pragma unroll
    for (int t = 0; t < 4; ++t) {
        int abase = ((wave + 4 * t) * 18 + col) * 8;
#pragma unroll
        for (int s = 0; s < 3; ++s) {
            v8h a = *(const v8h*)&s_x[abase + toff2[s]];
            acc0[t] = __builtin_amdgcn_mfma_f32_16x16x32_f16(a, bfB[s][0], acc0[t], 0, 0, 0);
            acc1[t] = __builtin_amdgcn_mfma_f32_16x16x32_f16(a, bfB[s][1], acc1[t], 0, 0, 0);
        }
    }

    // ---- gates from C-frags (write s_hc — disjoint from s_x, no barrier) ----
    const int c7 = lane & 7;
    const float g0v = fw[c7], g1v = fw[8 + c7], g2v = fw[16 + c7], g3v = fw[24 + c7];
#pragma unroll
    for (int t = 0; t < 4; ++t) {
        int mt = wave + 4 * t;
#pragma unroll
        for (int r = 0; r < 4; ++r) {
            float iu = __shfl_xor(acc0[t][r], 8, 64);
            if (col < 8) {
                float rr = 1.f / (1.f + __expf(-(acc0[t][r] + g0v)));
                float uu = 1.f / (1.f + __expf(-(iu + g1v)));
                float mm = acc1[t][r] + g2v + rr * g3v;
                mm = (mm >= 0.f) ? mm : 0.2f * mm;
                s_hc[(mt * 16 + quad * 4 + r) * 9 + c7] = (1.f - uu) * mm;
            }
        }
    }
    __syncthreads();

    // ---- conv_out (1x1, 8->12) ----
    float h[8];
#pragma unroll
    for (int c = 0; c < 8; ++c) h[c] = s_hc[tid * 9 + c];
    const float* wout = fw + 32;
    const float* bout = fw + 128;
    const int oy = tid >> 4, ox = tid & 15;
    float* op = out + (((size_t)b * 12) << 14) + ((ty0 + oy) << 7) + (tx0 + ox);
#pragma unroll
    for (int t = 0; t < 12; ++t) {
        float o = bout[t];
#pragma unroll
        for (int c = 0; c < 8; ++c) o = fmaf(h[c], wout[t * 8 + c], o);
        op[(size_t)t << 14] = o;
    }
}

extern "C" void kernel_launch(void* const* d_in, const int* in_sizes, int n_in,
                              void* d_out, int out_size, void* d_ws, size_t ws_size,
                              hipStream_t stream) {
    (void)in_sizes; (void)n_in; (void)ws_size; (void)out_size;
    const float* radar = (const float*)d_in[0];
    const float* pred  = (const float*)d_in[1];
    const float* w_in  = (const float*)d_in[2];
    const float* b_in  = (const float*)d_in[3];
    const float* w_i2h = (const float*)d_in[4];
    const float* b_i2h = (const float*)d_in[5];
    // d_in[6..12] (flow branch, w_ret) are dead: h0 == 0.
    const float* b_ret = (const float*)d_in[13];
    const float* w_out = (const float*)d_in[14];
    const float* b_out = (const float*)d_in[15];

    prep<<<(N_PREP + 255) / 256, 256, 0, stream>>>(w_in, b_in, w_i2h, b_i2h,
                                                   b_ret, w_out, b_out, d_ws);

    radar2_mfma<<<dim3(2048), dim3(256), 0, stream>>>(radar, pred, d_ws, (float*)d_out);
}

// Round 10
// 135.121 us; speedup vs baseline: 1.2361x; 1.2361x over previous
//
#include <hip/hip_runtime.h>
#include <hip/hip_bf16.h>

// RadarSecondStageGenerator — MFMA fp16, round 10: SPITCH=40 halfs (80 B) —
// 16B-aligned rows (keeps ds_read/write_b128, r9's 68 B pitch broke alignment
// and split every LDS access) AND bank-spread (start word 20·i mod 32 cycles
// 8 positions -> all 32 banks at min 8 accesses/bank, vs 64 B pitch's 2
// start positions / 8-way pileup). LDS 32 KB w/ s_x+s_hc aliased into dead
// s_in rows -> 5 blocks/CU.
//
// h0 == 0 ⇒ flow/warp/w_ret branch dead; network = conv3x3(24->8) ->
// conv3x3(8->24) -> GRU gates (h2h == b_ret) -> conv1x1(8->12).
//
// conv_in im2col: M = 324 x-halo px (21 tiles), N = 8, K = 9 taps x 32 ch
//   (ch 0..11 radar, 12..23 pred, 24 = ones channel carrying b_in at the
//   center tap, 25..31 zero pad) -> 9 MFMA (16x16x32) per M-tile.
// i2h: M = 256 px (16 tiles), N = 24 (2 N-tiles), K = 12 taps x 8 ch (3 steps).
// Fragment layouts (HW-verified): A[m=lane&15][k=quad*8+j], C[row=quad*4+reg][col=lane&15].

typedef __fp16   h2f __attribute__((ext_vector_type(2)));   // cvt_pkrtz return type
typedef _Float16 v8h __attribute__((ext_vector_type(8)));
typedef float    v4f __attribute__((ext_vector_type(4)));

#define HW 128
#define SPITCH 40        // halfs per staged position: 80 B, 16B-aligned + bank-spread

#define WB_HOFF 4608     // half-index of i2h B-frags in ws
#define FLT_OFF 16384    // byte offset of float params in ws
#define N_PREP  7820     // 4608 + 3072 halfs, then 140 floats

__global__ __launch_bounds__(256)
void prep(const float* __restrict__ w_in,  const float* __restrict__ b_in,
          const float* __restrict__ w_i2h, const float* __restrict__ b_i2h,
          const float* __restrict__ b_ret, const float* __restrict__ w_out,
          const float* __restrict__ b_out, void* __restrict__ ws)
{
    int idx = blockIdx.x * 256 + threadIdx.x;
    _Float16* wh = (_Float16*)ws;
    float* fw = (float*)((char*)ws + FLT_OFF);
    if (idx < 4608) {                       // conv_in B-frags [s9][lane64][j8]
        int j = idx & 7, r = idx >> 3;
        int lane = r & 63, s = r >> 6;      // s = tap 0..8
        int quad = lane >> 4, n = lane & 15;
        int ch = quad * 8 + j;              // k within step = channel 0..31
        float v = 0.f;
        if (n < 8) {
            if (ch < 24)                 v = w_in[n*216 + ch*9 + s];
            else if (ch == 24 && s == 4) v = b_in[n];   // ones-channel bias
        }
        wh[idx] = (_Float16)v;
    } else if (idx < 7680) {                // i2h B-frags [s3][nt2][lane64][j8]
        int i2 = idx - 4608;
        int j = i2 & 7, r = i2 >> 3;
        int lane = r & 63; r >>= 6;
        int nt = r & 1, s = r >> 1;
        int quad = lane >> 4, n = lane & 15;
        int kk = s * 32 + quad * 8 + j;     // K: tap-major, 8 ch per tap
        int t = kk >> 3, m = kk & 7;        // tap 0..11 (9..11 pad)
        int o = nt * 16 + n;
        float v = (t < 9 && o < 24) ? w_i2h[o*72 + m*9 + t] : 0.f;
        wh[WB_HOFF + i2] = (_Float16)v;
    } else if (idx < N_PREP) {
        int j = idx - 7680;
        float v;
        if (j < 32) {                       // combined gate biases
            int c = j & 7, sel = j >> 3;
            v = (sel==0) ? b_i2h[c]    + b_ret[c]
              : (sel==1) ? b_i2h[8+c]  + b_ret[8+c]
              : (sel==2) ? b_i2h[16+c] : b_ret[16+c];
        } else if (j < 128) v = w_out[j-32];
        else                v = b_out[j-128];
        fw[j] = v;
    }
}

__device__ __forceinline__ void pack_store(_Float16* dst, const float* v, bool ones)
{
    union { h2f h2[16]; v8h h8[4]; } u;
#pragma unroll
    for (int k = 0; k < 12; ++k)
        u.h2[k] = __builtin_amdgcn_cvt_pkrtz(v[2 * k], v[2 * k + 1]);
    u.h2[12] = __builtin_amdgcn_cvt_pkrtz(ones ? 1.f : 0.f, 0.f);
#pragma unroll
    for (int k = 13; k < 16; ++k) u.h2[k] = (h2f)0.f;
#pragma unroll
    for (int k = 0; k < 4; ++k) *(v8h*)&dst[8 * k] = u.h8[k];
}

__global__ __launch_bounds__(256, 5)
void radar2_mfma(const float* __restrict__ radar,  // (32,12,128,128)
                 const float* __restrict__ pred,   // (32,12,128,128)
                 const void*  __restrict__ ws,
                 float* __restrict__ out)          // (32,12,128,128)
{
    // Pool: s_in [400][SPITCH] f16 = 32000 B.
    // s_x  [336][8] f16 (5376 B)  aliases pool head (dead s_in rows after the
    //   post-conv_in barrier).
    // s_hc [256][9] f32 (9216 B)  at pool+5376 (disjoint from s_x).
    __shared__ __align__(16) char pool[400 * SPITCH * 2];
    _Float16* s_in = (_Float16*)pool;
    _Float16* s_x  = (_Float16*)pool;
    float*    s_hc = (float*)(pool + 5376);

    const _Float16* wh = (const _Float16*)ws;
    const float* fw = (const float*)((const char*)ws + FLT_OFF);

    const int tid  = threadIdx.x;
    const int lane = tid & 63;
    const int wave = tid >> 6;
    const int quad = lane >> 4;
    const int col  = lane & 15;

    // XCD-locality swizzle: id&7 = XCD (round-robin dispatch); each XCD's
    // 256-block stripe covers 4 whole batches -> halo reuse stays in one L2.
    const int id   = blockIdx.x;
    const int b    = (id & 7) * 4 + ((id >> 3) >> 6);
    const int tile = (id >> 3) & 63;
    const int ty0  = (tile >> 3) << 4;
    const int tx0  = (tile & 7) << 4;

    // ---- stage halo-2 patch, 25 live channels, channel-last; two slots with
    // all global loads issued before converts (max memory-level parallelism) ----
    const float* rb = radar + (((size_t)b * 12) << 14);
    const float* pb = pred  + (((size_t)b * 12) << 14);

    const int r0 = tid, r1 = tid + 256;
    const int ly0 = r0 / 20, lx0 = r0 - 20 * ly0;
    const int gy0 = ty0 + ly0 - 2, gx0 = tx0 + lx0 - 2;
    const bool in0 = ((unsigned)gy0 < HW) & ((unsigned)gx0 < HW);
    const int off0 = (gy0 << 7) + gx0;
    const bool has1 = (r1 < 400);
    const int ly1 = r1 / 20, lx1 = r1 - 20 * ly1;
    const int gy1 = ty0 + ly1 - 2, gx1 = tx0 + lx1 - 2;
    const bool in1 = has1 & ((unsigned)gy1 < HW) & ((unsigned)gx1 < HW);
    const int off1 = (gy1 << 7) + gx1;

    float va[24], vb24[24];
#pragma unroll
    for (int c = 0; c < 12; ++c) {
        va[c]      = in0 ? rb[((size_t)c << 14) + off0] : 0.f;
        va[12 + c] = in0 ? pb[((size_t)c << 14) + off0] : 0.f;
    }
#pragma unroll
    for (int c = 0; c < 12; ++c) {
        vb24[c]      = in1 ? rb[((size_t)c << 14) + off1] : 0.f;
        vb24[12 + c] = in1 ? pb[((size_t)c << 14) + off1] : 0.f;
    }
    pack_store(&s_in[r0 * SPITCH], va, in0);
    if (has1) pack_store(&s_in[r1 * SPITCH], vb24, in1);

    // conv_in B-frags — issued after staging stores; latency hides in barrier
    v8h bfA[9];
#pragma unroll
    for (int s = 0; s < 9; ++s) bfA[s] = *(const v8h*)&wh[(s * 64 + lane) * 8];
    __syncthreads();

    // ---- conv_in: 21 M-tiles over 4 waves, 9 MFMA each ----
    int pbase[6];
#pragma unroll
    for (int t = 0; t < 6; ++t) {
        int p = (wave + 4 * t) * 16 + col; if (p > 323) p = 323;
        pbase[t] = ((p / 18) * 20 + (p % 18)) * SPITCH + quad * 8;
    }
    v4f accA[6];
#pragma unroll
    for (int t = 0; t < 6; ++t) accA[t] = (v4f){0.f, 0.f, 0.f, 0.f};
#pragma unroll
    for (int t = 0; t < 6; ++t) {
        if (wave + 4 * t < 21) {
#pragma unroll
            for (int s = 0; s < 9; ++s) {
                v8h a = *(const v8h*)&s_in[pbase[t] + ((s / 3) * 20 + (s % 3)) * SPITCH];
                accA[t] = __builtin_amdgcn_mfma_f32_16x16x32_f16(a, bfA[s], accA[t], 0, 0, 0);
            }
        }
    }
    __syncthreads();   // all s_in reads complete before s_x overwrites pool head

    // ---- write s_x (x zero-padded outside the image) ----
    if (col < 8) {
#pragma unroll
        for (int t = 0; t < 6; ++t) {
            int mt = wave + 4 * t;
            if (mt < 21) {
#pragma unroll
                for (int r = 0; r < 4; ++r) {
                    int pa = mt * 16 + quad * 4 + r;
                    int py = pa / 18, px = pa - 18 * py;
                    bool ok = (pa < 324) &&
                              ((unsigned)(ty0 + py - 1) < HW) &&
                              ((unsigned)(tx0 + px - 1) < HW);
                    s_x[pa * 8 + col] = (_Float16)(ok ? accA[t][r] : 0.f);
                }
            }
        }
    }
    __syncthreads();

    // ---- i2h: 16 M-tiles, 3 K-steps, 2 N-tiles ----
    int toff2[3];
#pragma unroll
    for (int s = 0; s < 3; ++s) {
        int t = s * 4 + quad;
        toff2[s] = (t < 9) ? ((t / 3) * 18 + (t % 3)) * 8 : 0;
    }
    v8h bfB[3][2];
#pragma unroll
    for (int s = 0; s < 3; ++s)
#pragma unroll
        for (int nt = 0; nt < 2; ++nt)
            bfB[s][nt] = *(const v8h*)&wh[WB_HOFF + ((s * 2 + nt) * 64 + lane) * 8];

    v4f acc0[4], acc1[4];
#pragma unroll
    for (int t = 0; t < 4; ++t) {
        acc0[t] = (v4f){0.f, 0.f, 0.f, 0.f};
        acc1[t] = (v4f){0.f, 0.f, 0.f, 0.f};
    }
#pragma unroll
    for (int t = 0; t < 4; ++t) {
        int abase = ((wave + 4 * t) * 18 + col) * 8;
#pragma unroll
        for (int s = 0; s < 3; ++s) {
            v8h a = *(const v8h*)&s_x[abase + toff2[s]];
            acc0[t] = __builtin_amdgcn_mfma_f32_16x16x32_f16(a, bfB[s][0], acc0[t], 0, 0, 0);
            acc1[t] = __builtin_amdgcn_mfma_f32_16x16x32_f16(a, bfB[s][1], acc1[t], 0, 0, 0);
        }
    }

    // ---- gates from C-frags (write s_hc — disjoint from s_x, no barrier) ----
    const int c7 = lane & 7;
    const float g0v = fw[c7], g1v = fw[8 + c7], g2v = fw[16 + c7], g3v = fw[24 + c7];
#pragma unroll
    for (int t = 0; t < 4; ++t) {
        int mt = wave + 4 * t;
#pragma unroll
        for (int r = 0; r < 4; ++r) {
            float iu = __shfl_xor(acc0[t][r], 8, 64);
            if (col < 8) {
                float rr = 1.f / (1.f + __expf(-(acc0[t][r] + g0v)));
                float uu = 1.f / (1.f + __expf(-(iu + g1v)));
                float mm = acc1[t][r] + g2v + rr * g3v;
                mm = (mm >= 0.f) ? mm : 0.2f * mm;
                s_hc[(mt * 16 + quad * 4 + r) * 9 + c7] = (1.f - uu) * mm;
            }
        }
    }
    __syncthreads();

    // ---- conv_out (1x1, 8->12) ----
    float h[8];
#pragma unroll
    for (int c = 0; c < 8; ++c) h[c] = s_hc[tid * 9 + c];
    const float* wout = fw + 32;
    const float* bout = fw + 128;
    const int oy = tid >> 4, ox = tid & 15;
    float* op = out + (((size_t)b * 12) << 14) + ((ty0 + oy) << 7) + (tx0 + ox);
#pragma unroll
    for (int t = 0; t < 12; ++t) {
        float o = bout[t];
#pragma unroll
        for (int c = 0; c < 8; ++c) o = fmaf(h[c], wout[t * 8 + c], o);
        op[(size_t)t << 14] = o;
    }
}

extern "C" void kernel_launch(void* const* d_in, const int* in_sizes, int n_in,
                              void* d_out, int out_size, void* d_ws, size_t ws_size,
                              hipStream_t stream) {
    (void)in_sizes; (void)n_in; (void)ws_size; (void)out_size;
    const float* radar = (const float*)d_in[0];
    const float* pred  = (const float*)d_in[1];
    const float* w_in  = (const float*)d_in[2];
    const float* b_in  = (const float*)d_in[3];
    const float* w_i2h = (const float*)d_in[4];
    const float* b_i2h = (const float*)d_in[5];
    // d_in[6..12] (flow branch, w_ret) are dead: h0 == 0.
    const float* b_ret = (const float*)d_in[13];
    const float* w_out = (const float*)d_in[14];
    const float* b_out = (const float*)d_in[15];

    prep<<<(N_PREP + 255) / 256, 256, 0, stream>>>(w_in, b_in, w_i2h, b_i2h,
                                                   b_ret, w_out, b_out, d_ws);

    radar2_mfma<<<dim3(2048), dim3(256), 0, stream>>>(radar, pred, d_ws, (float*)d_out);
}